// Round 12
// baseline (499.322 us; speedup 1.0000x reference)
//
#include <hip/hip_runtime.h>
#include <hip/hip_bf16.h>

typedef unsigned short u16;
typedef unsigned int u32;
typedef __attribute__((ext_vector_type(8))) short short8;
typedef __attribute__((ext_vector_type(4))) float floatx4;

#define NPIX 12544   // 112*112 = 49 * 256
#define KDIM 768     // channels = 24 * 32
#define EPSF 1e-8f
#define NCH 24       // K chunks of 32
#define NTILE 49     // 12544 / 256

// ---------------------------------------------------------------- async G->LDS
__device__ __forceinline__ void gload_lds16(const void* g, void* l) {
  __builtin_amdgcn_global_load_lds(
      (const __attribute__((address_space(1))) void*)g,
      (__attribute__((address_space(3))) void*)l, 16, 0, 0);
}

// sortable-uint encoding of float (monotone): max over enc == max over float
__device__ __forceinline__ u32 enc_f32(float f) {
  u32 u = __float_as_uint(f);
  return (u & 0x80000000u) ? ~u : (u | 0x80000000u);
}
__device__ __forceinline__ float dec_f32(u32 e) {
  u32 u = (e & 0x80000000u) ? (e & 0x7FFFFFFFu) : ~e;
  return __uint_as_float(u);
}

// ---------------------------------------------------------------- K0: zero sumsq accumulators + atomic-max buffer
// grid 49, block 256
__global__ void zero_kernel(float* __restrict__ pa, float* __restrict__ pb,
                            u32* __restrict__ part) {
  int i = blockIdx.x * 256 + threadIdx.x;
  pa[i] = 0.f;
  pb[i] = 0.f;
  part[i] = 0u;  // encoded floor (< enc of any finite float)
}

// ---------------------------------------------------------------- K1: transpose + bf16 cast + FUSED sumsq
// (C,N) f32 -> (N,C) bf16, raw values (normalization in GEMM epilogue / finish:
// argmax_j (a_n.b_n) == argmax_j (a.b)*rb[j], cossim = max_j((a.b)*rb[j]) * ra[i], ra,rb>0).
// grid (392, 24, 2), block 256 (=32x8); per (row gi, 32-c block): 32-lane shfl reduce + 1 atomicAdd.
__global__ void transpose_kernel(const float* __restrict__ a, const float* __restrict__ b,
                                 u16* __restrict__ Ar, u16* __restrict__ Br,
                                 float* __restrict__ pa, float* __restrict__ pb) {
  const float* src = blockIdx.z ? b : a;
  u16* dst         = blockIdx.z ? Br : Ar;
  float* psum      = blockIdx.z ? pb : pa;
  __shared__ float tile[32][33];
  int i0 = blockIdx.x * 32;
  int c0 = blockIdx.y * 32;
  int tx = threadIdx.x & 31;
  int ty = threadIdx.x >> 5;  // 0..7
#pragma unroll
  for (int d = 0; d < 4; ++d) {
    int c = c0 + ty + d * 8;
    tile[ty + d * 8][tx] = src[(size_t)c * NPIX + i0 + tx];
  }
  __syncthreads();
#pragma unroll
  for (int d = 0; d < 4; ++d) {
    int il = ty + d * 8;
    int gi = i0 + il;
    float v = tile[tx][il];
    __hip_bfloat16 h = __float2bfloat16(v);
    dst[(size_t)gi * KDIM + c0 + tx] = *reinterpret_cast<u16*>(&h);
    float sq = v * v;
    sq += __shfl_xor(sq, 1);
    sq += __shfl_xor(sq, 2);
    sq += __shfl_xor(sq, 4);
    sq += __shfl_xor(sq, 8);
    sq += __shfl_xor(sq, 16);
    if (tx == 0) atomicAdd(&psum[gi], sq);
  }
}

// ---------------------------------------------------------------- K4: 256x256 tile, 8 waves,
// Round-12: B FRAGMENTS DIRECT FROM GLOBAL (L1/L2), LDS carries A only (64 KiB ring).
// Rationale: r11 accounting — per chunk 2930 cyc = MFMA 1242 (SIMD pipe) + LDS ~1400 (CU port:
// 96KB reads + 32KB DMA writes) + barriers. LDS port is a co-floor; schedule tuning can't pass
// max(1242,1400). Moving B (4 reads/wave/chunk, 16KB slice L1-resident, B panel L2-pinned per
// XCD) to plain global_load_dwordx4 into VGPRs: LDS/chunk 128->80KB; B's 32KB rides the
// parallel VMEM pipe; values/layout identical to the LDS path (bit-exact result).
// Structural bonus: B in registers => compiler auto-inserts exact counted vmcnt at the
// bfc=bfn copy (issue order: B(c+1) before STAGE_A(c+3) => vmcnt(2), A-stage stays in
// flight). Manual vmcnt only in the prologue. sched_barrier(0) after each s_barrier pins
// cross-barrier motion so the ledger holds:
//   - A(c+1) landed per-wave at chunk c-1's copy-wait, block-wide at bar(c) -> afn reads safe
//   - slot (c-1)&3 readers (af2@c-1, afn@c-2) lgkm-drained by their consuming MFMAs before
//     bar(c) -> STAGE_A(c+3) into that slot after bar(c) is safe
// Chunk c: {af2 ds_reads(slot c) | phi1 MFMA} -> bar -> {B(c+1) gloads; STAGE_A(c+3);
// afn ds_reads(slot c+1) | phi2 MFMA} -> copies. Tail: c21/c22 load B only; c23 bare.
// Swizzle (r5-proven, 0 conflicts) unchanged; A staging lane-linear (rule #21) unchanged.
// Dispatch (r7-proven balance): grid (8,301). Epilogue computes rb from pb inline (rnorm
// kernel deleted; part zeroed in K0).
__global__ __launch_bounds__(512, 2) void gemm_max_kernel(const u16* __restrict__ Ar,
                                                          const u16* __restrict__ Br,
                                                          const float* __restrict__ pb,
                                                          u32* __restrict__ part) {
  const int xcd = blockIdx.x;   // linear%8 round-robins XCDs
  const int idx = blockIdx.y;   // 0..300 sequence within XCD
  int ct, rt;
  if (idx < 294) {
    ct = (idx % 6) * 8 + xcd;   // cols {xcd, 8+xcd, ..., 40+xcd} -> B pinned per XCD
    rt = idx / 6;               // rows advance slowly, chip-synchronized
  } else {
    int j = (idx - 294) * 8 + xcd;  // col 48 remainder: rows round-robin XCDs
    if (j >= NTILE) return;         // 7 dead blocks (xcd>0 at idx==300)
    ct = 48; rt = j;
  }
  const int row_base = rt * 256;
  const int col_base = ct * 256;

  __shared__ alignas(16) u16 As[4 * 8192];  // A-only: 4 ring slots x [256 rows][4 slots][8]

  const int tid = threadIdx.x;
  const int lane = tid & 63;
  const int wid = tid >> 6;   // 0..7
  const int wm = wid >> 2;    // A half (0..1)
  const int wn = wid & 3;     // B quarter (0..3)
  const int l15 = lane & 15;
  const int quad = lane >> 4;

  // A staging (r11-verified): thread covers rows (tid>>2), (tid>>2)+128, 16B slot tid&3;
  // LDS dest tid*8 / +4096 lane-linear (rule #21); source pre-swizzled by clog.
  const int srow = tid >> 2;                       // 0..127
  const int clog = ((tid & 3) - (srow >> 1)) & 3;  // logical 8-elem k-group
  const u16* gAt = Ar + (size_t)(row_base + srow) * KDIM + clog * 8;
  u16* lA = &As[tid * 8];

#define STAGE_A(T)                                                             \
  do {                                                                         \
    gload_lds16(gAt + (T) * 32,              lA + (((T) & 3) << 13));          \
    gload_lds16(gAt + (T) * 32 + 128 * KDIM, lA + (((T) & 3) << 13) + 4096);   \
  } while (0)

  // A frag offsets within a slot: row R, k-quad quad -> R*32 + (((R>>1)+quad)&3)*8
  int aoff[8];
#pragma unroll
  for (int mm = 0; mm < 8; ++mm) {
    int R = wm * 128 + mm * 16 + l15;
    aoff[mm] = R * 32 + ((((R >> 1) + quad) & 3) << 3);
  }
  // B frag base pointers (global, row-major [col][k]): lane covers col, 16B k-group quad
  const u16* gBf[4];
#pragma unroll
  for (int nf = 0; nf < 4; ++nf)
    gBf[nf] = Br + (size_t)(col_base + wn * 64 + nf * 16 + l15) * KDIM + quad * 8;

#define LOADB(dst, T)                                                          \
  do {                                                                         \
    _Pragma("unroll") for (int nf = 0; nf < 4; ++nf)                           \
        dst[nf] = *(const short8*)&gBf[nf][(T) * 32];                          \
  } while (0)

  floatx4 acc[8][4];
#pragma unroll
  for (int m = 0; m < 8; ++m)
#pragma unroll
    for (int n = 0; n < 4; ++n) acc[m][n] = (floatx4){0.f, 0.f, 0.f, 0.f};

  short8 afc[4], bfc[4], bfn[4];

  // prologue: A slots 0..2 + B(0); vmcnt(2) drains A0,B0,A1 (A2 in flight); prime afc
  STAGE_A(0);
  LOADB(bfc, 0);
  STAGE_A(1); STAGE_A(2);
  asm volatile("s_waitcnt vmcnt(2)" ::: "memory");
  __builtin_amdgcn_s_barrier();
  __builtin_amdgcn_sched_barrier(0);
#pragma unroll
  for (int mm = 0; mm < 4; ++mm) afc[mm] = *(const short8*)&As[aoff[mm]];

#define CHUNK(C, DOB, DOSTG, DONEXT)                                                          \
  do {                                                                                        \
    const u16* pAs = &As[((C) & 3) << 13];                                                    \
    const u16* pAn = &As[(((C) + 1) & 3) << 13];                                              \
    short8 af2[4], afn[4];                                                                    \
    /* R1: af2 ds_reads (slot C) || phi1 MFMA (afc,bfc in regs) */                            \
    _Pragma("unroll") for (int mm = 0; mm < 4; ++mm)                                          \
        af2[mm] = *(const short8*)&pAs[aoff[mm + 4]];                                         \
    __builtin_amdgcn_s_setprio(1);                                                            \
    _Pragma("unroll") for (int mm = 0; mm < 4; ++mm)                                          \
      _Pragma("unroll") for (int nf = 0; nf < 4; ++nf)                                        \
          acc[mm][nf] = __builtin_amdgcn_mfma_f32_16x16x32_bf16(afc[mm], bfc[nf],             \
                                                                acc[mm][nf], 0, 0, 0);        \
    __builtin_amdgcn_s_setprio(0);                                                            \
    _Pragma("unroll") for (int g = 0; g < 4; ++g) {                                           \
      __builtin_amdgcn_sched_group_barrier(0x100, 1, 0); /* 1 ds_read */                      \
      __builtin_amdgcn_sched_group_barrier(0x008, 4, 0); /* 4 mfma    */                      \
    }                                                                                         \
    __builtin_amdgcn_s_barrier();        /* slot C+1 landed (copy-wait of C-1, block-wide */  \
    __builtin_amdgcn_sched_barrier(0);   /*  via this bar); slot (C-1)&3 readers done     */  \
    if (DOB) LOADB(bfn, (C) + 1);        /* B first, then A-stage: copy-wait => vmcnt(2)  */  \
    if (DOSTG) STAGE_A((C) + 3);                                                              \
    if (DONEXT) {                                                                             \
      _Pragma("unroll") for (int mm = 0; mm < 4; ++mm)                                        \
          afn[mm] = *(const short8*)&pAn[aoff[mm]];                                           \
    }                                                                                         \
    __builtin_amdgcn_s_setprio(1);                                                            \
    _Pragma("unroll") for (int mm = 0; mm < 4; ++mm)                                          \
      _Pragma("unroll") for (int nf = 0; nf < 4; ++nf)                                        \
          acc[mm + 4][nf] = __builtin_amdgcn_mfma_f32_16x16x32_bf16(af2[mm], bfc[nf],         \
                                                                    acc[mm + 4][nf], 0, 0, 0);\
    __builtin_amdgcn_s_setprio(0);                                                            \
    _Pragma("unroll") for (int g = 0; g < 4; ++g) {                                           \
      __builtin_amdgcn_sched_group_barrier(0x100, 1, 0);                                      \
      __builtin_amdgcn_sched_group_barrier(0x008, 4, 0);                                      \
    }                                                                                         \
    if (DONEXT) {                                                                             \
      _Pragma("unroll") for (int mm = 0; mm < 4; ++mm) afc[mm] = afn[mm];                     \
      _Pragma("unroll") for (int nf = 0; nf < 4; ++nf) bfc[nf] = bfn[nf];                     \
    }                                                                                         \
  } while (0)

  CHUNK(0,  1, 1, 1);  CHUNK(1,  1, 1, 1);  CHUNK(2,  1, 1, 1);  CHUNK(3,  1, 1, 1);
  CHUNK(4,  1, 1, 1);  CHUNK(5,  1, 1, 1);  CHUNK(6,  1, 1, 1);  CHUNK(7,  1, 1, 1);
  CHUNK(8,  1, 1, 1);  CHUNK(9,  1, 1, 1);  CHUNK(10, 1, 1, 1);  CHUNK(11, 1, 1, 1);
  CHUNK(12, 1, 1, 1);  CHUNK(13, 1, 1, 1);  CHUNK(14, 1, 1, 1);  CHUNK(15, 1, 1, 1);
  CHUNK(16, 1, 1, 1);  CHUNK(17, 1, 1, 1);  CHUNK(18, 1, 1, 1);  CHUNK(19, 1, 1, 1);
  CHUNK(20, 1, 1, 1);
  CHUNK(21, 1, 0, 1);   // B(22); no stage (A ends at slot for chunk 23)
  CHUNK(22, 1, 0, 1);   // B(23)
  CHUNK(23, 0, 0, 0);

#undef CHUNK
#undef STAGE_A
#undef LOADB

  // epilogue: per-row max over the 256-col tile of acc * rb[col], rb computed from pb.
  // C frag layout: col = l15 (+nf*16), row = quad*4 + rr (+m*16, +wm*128)
  float rbv[4];
#pragma unroll
  for (int nf = 0; nf < 4; ++nf) {
    float s = pb[col_base + wn * 64 + nf * 16 + l15];
    rbv[nf] = 1.f / (sqrtf(s + EPSF) + EPSF);
  }

  // s_max overlays As slot 0 (last slot-0 reads: chunk 20 af2 / chunk 19 afn, lgkm-drained
  // by their consuming MFMAs; __syncthreads below orders all waves before writes)
  float* s_max = reinterpret_cast<float*>(&As[0]);
  __syncthreads();
#pragma unroll
  for (int m = 0; m < 8; ++m) {
#pragma unroll
    for (int rr = 0; rr < 4; ++rr) {
      float best = fmaxf(fmaxf(acc[m][0][rr] * rbv[0], acc[m][1][rr] * rbv[1]),
                         fmaxf(acc[m][2][rr] * rbv[2], acc[m][3][rr] * rbv[3]));
      best = fmaxf(best, __shfl_xor(best, 1));
      best = fmaxf(best, __shfl_xor(best, 2));
      best = fmaxf(best, __shfl_xor(best, 4));
      best = fmaxf(best, __shfl_xor(best, 8));
      if (l15 == 0)
        s_max[wn * 256 + wm * 128 + m * 16 + quad * 4 + rr] = best;  // unique writer per entry
    }
  }
  __syncthreads();
  if (tid < 256) {
    float mx = fmaxf(fmaxf(s_max[tid], s_max[256 + tid]),
                     fmaxf(s_max[512 + tid], s_max[768 + tid]));
    atomicMax(&part[row_base + tid], enc_f32(mx));
  }
}

// ---------------------------------------------------------------- K5: decode + apply ra + loss
// single block, 1024 threads; ra computed inline from pa (rnorm kernel deleted).
__global__ void finish_kernel(const u32* __restrict__ part, const float* __restrict__ pa,
                              float* __restrict__ out) {
  float v = 0.f;
  for (int i = threadIdx.x; i < NPIX; i += 1024) {
    float ra = 1.f / (sqrtf(pa[i] + EPSF) + EPSF);
    v += 1.0f - dec_f32(part[i]) * ra;
  }
#pragma unroll
  for (int off = 32; off > 0; off >>= 1) v += __shfl_down(v, off);
  __shared__ float red[16];
  int w = threadIdx.x >> 6;
  if ((threadIdx.x & 63) == 0) red[w] = v;
  __syncthreads();
  if (threadIdx.x == 0) {
    float s = 0.f;
#pragma unroll
    for (int k = 0; k < 16; ++k) s += red[k];
    out[0] = s * (1.0f / (float)NPIX);
  }
}

// ---------------------------------------------------------------- launcher
extern "C" void kernel_launch(void* const* d_in, const int* in_sizes, int n_in,
                              void* d_out, int out_size, void* d_ws, size_t ws_size,
                              hipStream_t stream) {
  const float* x = (const float*)d_in[0];
  const float* s = (const float*)d_in[1];
  char* ws = (char*)d_ws;
  // layout (bytes):
  float* pa   = (float*)(ws + 0);         //    50176 (sumsq accum)
  float* pb   = (float*)(ws + 401408);    //    50176
  u32*   part = (u32*)  (ws + 903168);    //    50176 (encoded row maxima)
  u16*   Ar   = (u16*)  (ws + 953344);    // 19267584
  u16*   Br   = (u16*)  (ws + 20220928);  // 19267584  -> total 39488512 B

  zero_kernel<<<49, 256, 0, stream>>>(pa, pb, part);
  transpose_kernel<<<dim3(392, 24, 2), 256, 0, stream>>>(x, s, Ar, Br, pa, pb);
  gemm_max_kernel<<<dim3(8, 301), 512, 0, stream>>>(Ar, Br, pb, part);
  finish_kernel<<<1, 1024, 0, stream>>>(part, pa, (float*)d_out);
}

// Round 13
// 390.216 us; speedup vs baseline: 1.2796x; 1.2796x over previous
//
#include <hip/hip_runtime.h>
#include <hip/hip_bf16.h>

typedef unsigned short u16;
typedef unsigned int u32;
typedef __attribute__((ext_vector_type(8))) short short8;
typedef __attribute__((ext_vector_type(4))) float floatx4;

#define NPIX 12544   // 112*112 = 49 * 256
#define KDIM 768     // channels = 24 * 32
#define EPSF 1e-8f
#define NCH 24       // K chunks of 32
#define NTILE 49     // 12544 / 256

// ---------------------------------------------------------------- async G->LDS
__device__ __forceinline__ void gload_lds16(const void* g, void* l) {
  __builtin_amdgcn_global_load_lds(
      (const __attribute__((address_space(1))) void*)g,
      (__attribute__((address_space(3))) void*)l, 16, 0, 0);
}

// sortable-uint encoding of float (monotone): max over enc == max over float
__device__ __forceinline__ u32 enc_f32(float f) {
  u32 u = __float_as_uint(f);
  return (u & 0x80000000u) ? ~u : (u | 0x80000000u);
}
__device__ __forceinline__ float dec_f32(u32 e) {
  u32 u = (e & 0x80000000u) ? (e & 0x7FFFFFFFu) : ~e;
  return __uint_as_float(u);
}

// ---------------------------------------------------------------- K0: zero sumsq accumulators + atomic-max buffer
// grid 49, block 256
__global__ void zero_kernel(float* __restrict__ pa, float* __restrict__ pb,
                            u32* __restrict__ part) {
  int i = blockIdx.x * 256 + threadIdx.x;
  pa[i] = 0.f;
  pb[i] = 0.f;
  part[i] = 0u;  // encoded floor (< enc of any finite float)
}

// ---------------------------------------------------------------- K1: transpose + bf16 cast + FUSED sumsq
// (C,N) f32 -> (N,C) bf16, raw values (normalization in GEMM epilogue / finish:
// argmax_j (a_n.b_n) == argmax_j (a.b)*rb[j], cossim = max_j((a.b)*rb[j]) * ra[i], ra,rb>0).
// grid (392, 24, 2), block 256 (=32x8); per (row gi, 32-c block): 32-lane shfl reduce + 1 atomicAdd.
__global__ void transpose_kernel(const float* __restrict__ a, const float* __restrict__ b,
                                 u16* __restrict__ Ar, u16* __restrict__ Br,
                                 float* __restrict__ pa, float* __restrict__ pb) {
  const float* src = blockIdx.z ? b : a;
  u16* dst         = blockIdx.z ? Br : Ar;
  float* psum      = blockIdx.z ? pb : pa;
  __shared__ float tile[32][33];
  int i0 = blockIdx.x * 32;
  int c0 = blockIdx.y * 32;
  int tx = threadIdx.x & 31;
  int ty = threadIdx.x >> 5;  // 0..7
#pragma unroll
  for (int d = 0; d < 4; ++d) {
    int c = c0 + ty + d * 8;
    tile[ty + d * 8][tx] = src[(size_t)c * NPIX + i0 + tx];
  }
  __syncthreads();
#pragma unroll
  for (int d = 0; d < 4; ++d) {
    int il = ty + d * 8;
    int gi = i0 + il;
    float v = tile[tx][il];
    __hip_bfloat16 h = __float2bfloat16(v);
    dst[(size_t)gi * KDIM + c0 + tx] = *reinterpret_cast<u16*>(&h);
    float sq = v * v;
    sq += __shfl_xor(sq, 1);
    sq += __shfl_xor(sq, 2);
    sq += __shfl_xor(sq, 4);
    sq += __shfl_xor(sq, 8);
    sq += __shfl_xor(sq, 16);
    if (tx == 0) atomicAdd(&psum[gi], sq);
  }
}

// ---------------------------------------------------------------- K4: 256x256 tile, 8 waves,
// Round-13: REVERT to the r7-exact ring GEMM (best measured: 274.6us / 39% MfmaUtil),
// keeping r11/r12 aux wins (fused sumsq, rnorm deleted, rb from pb in epilogue).
// r12 lesson: B frags direct-from-global are a 64-cache-line gather per load (lane stride
// 1536B) — VMEM serializes, MfmaUtil 24%. B belongs in LDS (coalesced once via staging).
// r11 lesson: vmcnt(8) at the wait point (only 8 outstanding) is a NO-OP wait — lost the
// slot-landed guarantee and 16us. vmcnt(4) restored.
// Structure (r7-proven): K split into 24 chunks of BK=32; LDS = 4 ring slots per matrix
// (slot = chunk&3, 16KB each; 128 KiB total, 1 block/CU). Chunk c body:
//   R1: af2 ds_reads (slot c) || phi1 MFMA (pre-read frags), SGB ladder {1 DS_READ,4 MFMA}x4
//   vmcnt(4) [c+1's 4 stages landed; c+2's 4 in flight] + barrier + sched_barrier
//   STAGE4(c+3) -> slot (c-1)&3 [readers lgkm-drained before the barrier]
//   R2: next-chunk frag reads (slot c+1) || phi2 MFMA, SGB ladder {1 DS_READ,2 MFMA}x8
// Tail: c21 vmcnt(4) [c22 landed], c22 vmcnt(0), c23 bare. Never drains mid-loop.
// Swizzle (r5-proven, 0 conflicts): LDS(row r, 16B-slot s) holds k-group (s-(r>>1))&3;
// global source pre-swizzled, LDS dest lane-linear (rule #21).
// Dispatch (r7-proven balance): grid (8,301): XCD k owns cols {k,k+8,...,k+40}, rt slow
// chip-synced; col-48 remainder round-robins rows across XCDs. 300/301 blocks per XCD.
__global__ __launch_bounds__(512, 2) void gemm_max_kernel(const u16* __restrict__ Ar,
                                                          const u16* __restrict__ Br,
                                                          const float* __restrict__ pb,
                                                          u32* __restrict__ part) {
  const int xcd = blockIdx.x;   // linear%8 round-robins XCDs
  const int idx = blockIdx.y;   // 0..300 sequence within XCD
  int ct, rt;
  if (idx < 294) {
    ct = (idx % 6) * 8 + xcd;   // cols {xcd, 8+xcd, ..., 40+xcd} -> B pinned per XCD
    rt = idx / 6;               // rows advance slowly, chip-synchronized
  } else {
    int j = (idx - 294) * 8 + xcd;  // col 48 remainder: rows round-robin XCDs
    if (j >= NTILE) return;         // 7 dead blocks (xcd>0 at idx==300)
    ct = 48; rt = j;
  }
  const int row_base = rt * 256;
  const int col_base = ct * 256;

  __shared__ alignas(16) u16 As[4 * 8192];  // 4 ring slots: [256 rows][4 slots][8 elems]
  __shared__ alignas(16) u16 Bs[4 * 8192];

  const int tid = threadIdx.x;
  const int lane = tid & 63;
  const int wid = tid >> 6;   // 0..7
  const int wm = wid >> 2;    // A half (0..1)
  const int wn = wid & 3;     // B quarter (0..3)
  const int l15 = lane & 15;
  const int quad = lane >> 4;

  // staging: thread covers rows (tid>>2) and (tid>>2)+128, 16B slot tid&3.
  const int srow = tid >> 2;                       // 0..127
  const int clog = ((tid & 3) - (srow >> 1)) & 3;  // logical 8-elem k-group (pre-swizzled)
  const u16* gAt = Ar + (size_t)(row_base + srow) * KDIM + clog * 8;
  const u16* gBt = Br + (size_t)(col_base + srow) * KDIM + clog * 8;
  u16* lA = &As[tid * 8];
  u16* lB = &Bs[tid * 8];

#define STAGE4(T)                                                              \
  do {                                                                         \
    gload_lds16(gAt + (T) * 32,              lA + (((T) & 3) << 13));          \
    gload_lds16(gAt + (T) * 32 + 128 * KDIM, lA + (((T) & 3) << 13) + 4096);   \
    gload_lds16(gBt + (T) * 32,              lB + (((T) & 3) << 13));          \
    gload_lds16(gBt + (T) * 32 + 128 * KDIM, lB + (((T) & 3) << 13) + 4096);   \
  } while (0)

  // frag element offsets within a slot: row R, k-quad quad -> R*32 + (((R>>1)+quad)&3)*8
  int aoff[8], boff[4];
#pragma unroll
  for (int mm = 0; mm < 8; ++mm) {
    int R = wm * 128 + mm * 16 + l15;
    aoff[mm] = R * 32 + ((((R >> 1) + quad) & 3) << 3);
  }
#pragma unroll
  for (int nf = 0; nf < 4; ++nf) {
    int Cc = wn * 64 + nf * 16 + l15;
    boff[nf] = Cc * 32 + ((((Cc >> 1) + quad) & 3) << 3);
  }

  floatx4 acc[8][4];
#pragma unroll
  for (int m = 0; m < 8; ++m)
#pragma unroll
    for (int n = 0; n < 4; ++n) acc[m][n] = (floatx4){0.f, 0.f, 0.f, 0.f};

  // prologue: stage chunks 0,1,2; wait chunk 0 landed (1,2 stay in flight); prime frags
  STAGE4(0); STAGE4(1); STAGE4(2);
  asm volatile("s_waitcnt vmcnt(8)" ::: "memory");
  __builtin_amdgcn_s_barrier();
  __builtin_amdgcn_sched_barrier(0);

  short8 afc[4], bfc[4];
#pragma unroll
  for (int mm = 0; mm < 4; ++mm) afc[mm] = *(const short8*)&As[aoff[mm]];
#pragma unroll
  for (int nf = 0; nf < 4; ++nf) bfc[nf] = *(const short8*)&Bs[boff[nf]];

#define CHUNK(C, DOSTG, VMSTR, DOWAIT, DONEXT)                                                \
  do {                                                                                        \
    const u16* pAs = &As[((C) & 3) << 13];                                                    \
    const u16* pBs = &Bs[((C) & 3) << 13];                                                    \
    const u16* pAn = &As[(((C) + 1) & 3) << 13];                                              \
    const u16* pBn = &Bs[(((C) + 1) & 3) << 13];                                              \
    (void)pBs;                                                                                \
    short8 af2[4], afn[4], bfn[4];                                                            \
    /* R1: af2 reads (slot C) || phi1 MFMA (afc,bfc ready in regs) */                         \
    _Pragma("unroll") for (int mm = 0; mm < 4; ++mm)                                          \
        af2[mm] = *(const short8*)&pAs[aoff[mm + 4]];                                         \
    _Pragma("unroll") for (int mm = 0; mm < 4; ++mm)                                          \
      _Pragma("unroll") for (int nf = 0; nf < 4; ++nf)                                        \
          acc[mm][nf] = __builtin_amdgcn_mfma_f32_16x16x32_bf16(afc[mm], bfc[nf],             \
                                                                acc[mm][nf], 0, 0, 0);        \
    _Pragma("unroll") for (int g = 0; g < 4; ++g) {                                           \
      __builtin_amdgcn_sched_group_barrier(0x100, 1, 0); /* 1 ds_read      */                 \
      __builtin_amdgcn_sched_group_barrier(0x008, 4, 0); /* 4 mfma         */                 \
    }                                                                                         \
    if (DOWAIT) {                                                                             \
      asm volatile("s_waitcnt " VMSTR ::: "memory");                                          \
      __builtin_amdgcn_s_barrier();           /* slot C+1 landed; C-1 reads all done */       \
      __builtin_amdgcn_sched_barrier(0);                                                      \
    }                                                                                         \
    if (DOSTG) STAGE4((C) + 3);                                                               \
    /* R2: next-chunk frag reads (slot C+1) || phi2 MFMA (af2 from R1, lgkm-covered) */       \
    if (DONEXT) {                                                                             \
      _Pragma("unroll") for (int mm = 0; mm < 4; ++mm)                                        \
          afn[mm] = *(const short8*)&pAn[aoff[mm]];                                           \
      _Pragma("unroll") for (int nf = 0; nf < 4; ++nf)                                        \
          bfn[nf] = *(const short8*)&pBn[boff[nf]];                                           \
    }                                                                                         \
    _Pragma("unroll") for (int mm = 0; mm < 4; ++mm)                                          \
      _Pragma("unroll") for (int nf = 0; nf < 4; ++nf)                                        \
          acc[mm + 4][nf] = __builtin_amdgcn_mfma_f32_16x16x32_bf16(af2[mm], bfc[nf],         \
                                                                    acc[mm + 4][nf], 0, 0, 0);\
    if (DONEXT) {                                                                             \
      _Pragma("unroll") for (int g = 0; g < 8; ++g) {                                         \
        __builtin_amdgcn_sched_group_barrier(0x100, 1, 0); /* 1 ds_read    */                 \
        __builtin_amdgcn_sched_group_barrier(0x008, 2, 0); /* 2 mfma       */                 \
      }                                                                                       \
      _Pragma("unroll") for (int mm = 0; mm < 4; ++mm) afc[mm] = afn[mm];                     \
      _Pragma("unroll") for (int nf = 0; nf < 4; ++nf) bfc[nf] = bfn[nf];                     \
    }                                                                                         \
  } while (0)

  // vmcnt ledger (r7-exact): at chunk C's wait, outstanding = stages for C+1 (issued C-2)
  // and C+2 (issued C-1) = 8 loads; vmcnt(4) -> C+1's 4 landed, C+2's 4 in flight.
  // Tail: c21 outstanding c22+c23 -> vmcnt(4) = c22 landed; c22 -> vmcnt(0); c23 bare.
  CHUNK(0,  1, "vmcnt(4)", 1, 1);  CHUNK(1,  1, "vmcnt(4)", 1, 1);
  CHUNK(2,  1, "vmcnt(4)", 1, 1);  CHUNK(3,  1, "vmcnt(4)", 1, 1);
  CHUNK(4,  1, "vmcnt(4)", 1, 1);  CHUNK(5,  1, "vmcnt(4)", 1, 1);
  CHUNK(6,  1, "vmcnt(4)", 1, 1);  CHUNK(7,  1, "vmcnt(4)", 1, 1);
  CHUNK(8,  1, "vmcnt(4)", 1, 1);  CHUNK(9,  1, "vmcnt(4)", 1, 1);
  CHUNK(10, 1, "vmcnt(4)", 1, 1);  CHUNK(11, 1, "vmcnt(4)", 1, 1);
  CHUNK(12, 1, "vmcnt(4)", 1, 1);  CHUNK(13, 1, "vmcnt(4)", 1, 1);
  CHUNK(14, 1, "vmcnt(4)", 1, 1);  CHUNK(15, 1, "vmcnt(4)", 1, 1);
  CHUNK(16, 1, "vmcnt(4)", 1, 1);  CHUNK(17, 1, "vmcnt(4)", 1, 1);
  CHUNK(18, 1, "vmcnt(4)", 1, 1);  CHUNK(19, 1, "vmcnt(4)", 1, 1);
  CHUNK(20, 1, "vmcnt(4)", 1, 1);
  CHUNK(21, 0, "vmcnt(4)", 1, 1);
  CHUNK(22, 0, "vmcnt(0)", 1, 1);
  CHUNK(23, 0, "vmcnt(0)", 0, 0);

#undef CHUNK
#undef STAGE4

  // epilogue: per-row max over the 256-col tile of acc * rb[col], rb computed from pb.
  // C frag layout: col = l15 (+nf*16), row = quad*4 + rr (+m*16, +wm*128)
  float rbv[4];
#pragma unroll
  for (int nf = 0; nf < 4; ++nf) {
    float s = pb[col_base + wn * 64 + nf * 16 + l15];
    rbv[nf] = 1.f / (sqrtf(s + EPSF) + EPSF);
  }

  // s_max overlays As slot 0 (last slot-0 reads: chunk 20, lgkm-drained by their consuming
  // MFMAs before the chunk-21/22 barriers); __syncthreads orders all waves before writes.
  float* s_max = reinterpret_cast<float*>(&As[0]);
  __syncthreads();
#pragma unroll
  for (int m = 0; m < 8; ++m) {
#pragma unroll
    for (int rr = 0; rr < 4; ++rr) {
      float best = fmaxf(fmaxf(acc[m][0][rr] * rbv[0], acc[m][1][rr] * rbv[1]),
                         fmaxf(acc[m][2][rr] * rbv[2], acc[m][3][rr] * rbv[3]));
      best = fmaxf(best, __shfl_xor(best, 1));
      best = fmaxf(best, __shfl_xor(best, 2));
      best = fmaxf(best, __shfl_xor(best, 4));
      best = fmaxf(best, __shfl_xor(best, 8));
      if (l15 == 0)
        s_max[wn * 256 + wm * 128 + m * 16 + quad * 4 + rr] = best;  // unique writer per entry
    }
  }
  __syncthreads();
  if (tid < 256) {
    float mx = fmaxf(fmaxf(s_max[tid], s_max[256 + tid]),
                     fmaxf(s_max[512 + tid], s_max[768 + tid]));
    atomicMax(&part[row_base + tid], enc_f32(mx));
  }
}

// ---------------------------------------------------------------- K5: decode + apply ra + loss
// single block, 1024 threads; ra computed inline from pa (rnorm kernel deleted).
__global__ void finish_kernel(const u32* __restrict__ part, const float* __restrict__ pa,
                              float* __restrict__ out) {
  float v = 0.f;
  for (int i = threadIdx.x; i < NPIX; i += 1024) {
    float ra = 1.f / (sqrtf(pa[i] + EPSF) + EPSF);
    v += 1.0f - dec_f32(part[i]) * ra;
  }
#pragma unroll
  for (int off = 32; off > 0; off >>= 1) v += __shfl_down(v, off);
  __shared__ float red[16];
  int w = threadIdx.x >> 6;
  if ((threadIdx.x & 63) == 0) red[w] = v;
  __syncthreads();
  if (threadIdx.x == 0) {
    float s = 0.f;
#pragma unroll
    for (int k = 0; k < 16; ++k) s += red[k];
    out[0] = s * (1.0f / (float)NPIX);
  }
}

// ---------------------------------------------------------------- launcher
extern "C" void kernel_launch(void* const* d_in, const int* in_sizes, int n_in,
                              void* d_out, int out_size, void* d_ws, size_t ws_size,
                              hipStream_t stream) {
  const float* x = (const float*)d_in[0];
  const float* s = (const float*)d_in[1];
  char* ws = (char*)d_ws;
  // layout (bytes):
  float* pa   = (float*)(ws + 0);         //    50176 (sumsq accum)
  float* pb   = (float*)(ws + 401408);    //    50176
  u32*   part = (u32*)  (ws + 903168);    //    50176 (encoded row maxima)
  u16*   Ar   = (u16*)  (ws + 953344);    // 19267584
  u16*   Br   = (u16*)  (ws + 20220928);  // 19267584  -> total 39488512 B

  zero_kernel<<<49, 256, 0, stream>>>(pa, pb, part);
  transpose_kernel<<<dim3(392, 24, 2), 256, 0, stream>>>(x, s, Ar, Br, pa, pb);
  gemm_max_kernel<<<dim3(8, 301), 512, 0, stream>>>(Ar, Br, pb, part);
  finish_kernel<<<1, 1024, 0, stream>>>(part, pa, (float*)d_out);
}